// Round 1
// 179.478 us; speedup vs baseline: 1.0140x; 1.0140x over previous
//
#include <hip/hip_runtime.h>

// BoundarySeg: B=16, L=1024, H=768, MAX_SPAN_LEN=6 — all fp32
//   w[b,j,d]     = span[b, j, min(j+d,L-1), 0] * (j+d < L)
//   first[b,j,h] = sum_d w[b,j,d] * bound[b, min(j+d,L-1), h]
//   second[b,j,h]= bound[b,j,h] * sum_d w[b,j,d]
//   out = concat(first, second, axis=-1) -> (B, L, 1536)
//
// R5 theory: dur_us(182) = ~2 fixed re-poison fills (118 us) + kernel (~62 us).
// Kernel roofline: 82 MB read + 101 MB write = 185 MB @ 6.8 TB/s = ~28 us, so
// kernel is 2.2x off. Suspects: stage->barrier->compute convoy (no R/W overlap),
// nt-store path, VGPR round-trip staging. R5 = streaming pipeline:
//   * 512 blocks x 192 thr (3 waves), 4 consecutive 8-row tiles per block
//   * LDS double-buffer 2x13 rows (80.4 KB -> exactly 2 blocks/CU, all resident)
//   * global_load_lds (16 B) stages tile t+1 BEFORE compute/store of tile t;
//     the barrier's vmcnt(0) drain overlaps next-tile reads with cur-tile stores
//   * 192 threads => staging is exactly 13 x 192 f32x4: no div/mod, and each
//     64-lane group hits one row contiguously (global_load_lds dst constraint)
//   * compute keeps the 13-row column in regs: 13 ds_read_b128 + 8 outputs
//   * plain f32x4 stores (fills prove plain stores reach 6.8 TB/s)
// Predict kernel ~62 -> ~30 us, dur_us -> ~150. If dur_us unchanged (+-4),
// timed region is fill-dominated -> kernel already at floor.

#define LROWS 1024
#define HDIM  768
#define SPANW 6
#define TILE_J 8
#define STAGE 13                 // TILE_J + SPANW - 1
#define VPR   (HDIM / 4)         // 192 f32x4 per row
#define NT    4                  // tiles per block
#define BLK   192                // threads = 3 waves

typedef float f32x4 __attribute__((ext_vector_type(4)));

__device__ __forceinline__ void gload16(const float* g, float* l) {
    __builtin_amdgcn_global_load_lds(
        (const __attribute__((address_space(1))) void*)g,
        (__attribute__((address_space(3))) void*)l,
        16, 0, 0);
}

__global__ __launch_bounds__(BLK) void boundary_seg_kernel(
    const float* __restrict__ span,   // (B, L, L, 1)
    const float* __restrict__ bound,  // (B, L, H)
    float* __restrict__ out)          // (B, L, 2H)
{
    __shared__ __align__(16) float sb[2][STAGE * HDIM]; // 2 x 39,936 B
    __shared__ __align__(16) float sw[2][TILE_J][8];    // padded rows; [6],[7]=0

    const int tid   = threadIdx.x;
    const int b     = blockIdx.x >> 5;                  // 32 blocks per batch
    const int strip = (blockIdx.x & 31) * (NT * TILE_J);
    const int bL    = b * LROWS;

    // span-lane decomposition (wave 0 only): 8 rows x 8 slots, slots 6,7 -> 0
    const int sr = tid >> 3;
    const int sd = tid & 7;

    // ---- prologue: stage tile 0 into buf 0
    {
        const int jt0 = strip;
#pragma unroll
        for (int r = 0; r < STAGE; ++r) {
            int gr = jt0 + r; if (gr > LROWS - 1) gr = LROWS - 1;
            gload16(bound + (size_t)(bL + gr) * HDIM + (tid << 2),
                    &sb[0][r * HDIM + (tid << 2)]);
        }
        if (tid < 64) {
            const int j = jt0 + sr;
            float wd = 0.f;
            if (sd < SPANW && j + sd < LROWS)
                wd = span[(size_t)(bL + j) * LROWS + j + sd];
            sw[0][sr][sd] = wd;
        }
    }
    __syncthreads();   // drains gload_lds (vmcnt) + ds_write: buf0 ready

#pragma unroll
    for (int t = 0; t < NT; ++t) {
        const int cur = t & 1, nxt = cur ^ 1;
        const int jt0 = strip + t * TILE_J;

        // ---- issue stage of tile t+1 FIRST (hides under compute+stores)
        float wreg = 0.f;
        if (t < NT - 1) {
            const int jn = jt0 + TILE_J;
#pragma unroll
            for (int r = 0; r < STAGE; ++r) {
                int gr = jn + r; if (gr > LROWS - 1) gr = LROWS - 1;
                gload16(bound + (size_t)(bL + gr) * HDIM + (tid << 2),
                        &sb[nxt][r * HDIM + (tid << 2)]);
            }
            if (tid < 64) {
                const int j = jn + sr;
                if (sd < SPANW && j + sd < LROWS)
                    wreg = span[(size_t)(bL + j) * LROWS + j + sd];
            }
        }
        __builtin_amdgcn_sched_barrier(0);  // pin: stage issued before compute

        // ---- compute tile t from buf[cur]: thread owns one f32x4 column
        const f32x4* sb4 = (const f32x4*)&sb[cur][0];
        f32x4 h[STAGE];
#pragma unroll
        for (int r = 0; r < STAGE; ++r) h[r] = sb4[r * VPR + tid];

#pragma unroll
        for (int jj = 0; jj < TILE_J; ++jj) {
            const f32x4 w0 = *(const f32x4*)&sw[cur][jj][0];
            const f32x4 w1 = *(const f32x4*)&sw[cur][jj][4]; // [2],[3] are 0
            f32x4 acc = w0[0] * h[jj]     + w0[1] * h[jj + 1]
                      + w0[2] * h[jj + 2] + w0[3] * h[jj + 3]
                      + w1[0] * h[jj + 4] + w1[1] * h[jj + 5];
            const float wsum = w0[0] + w0[1] + w0[2] + w0[3] + w1[0] + w1[1];
            const f32x4 sec = h[jj] * wsum;

            float* orow = out + (size_t)(bL + jt0 + jj) * (2 * HDIM) + (tid << 2);
            *(f32x4*)orow          = acc;   // plain stores: fills hit 6.8 TB/s
            *(f32x4*)(orow + HDIM) = sec;
        }

        // ---- publish next tile's weights (span vmcnt wait hid under compute)
        if (t < NT - 1 && tid < 64) sw[nxt][sr][sd] = wreg;
        __syncthreads();   // drain: buf[nxt] staged + sw visible
    }
}

extern "C" void kernel_launch(void* const* d_in, const int* in_sizes, int n_in,
                              void* d_out, int out_size, void* d_ws, size_t ws_size,
                              hipStream_t stream) {
    const float* span  = (const float*)d_in[0];
    const float* bound = (const float*)d_in[1];
    float* out = (float*)d_out;

    const int B = in_sizes[1] / (LROWS * HDIM);     // 16 (element counts)
    dim3 grid(B * (LROWS / (NT * TILE_J))), block(BLK);   // 512 x 192
    hipLaunchKernelGGL(boundary_seg_kernel, grid, block, 0, stream,
                       span, bound, out);
}